// Round 1
// baseline (155.239 us; speedup 1.0000x reference)
//
#include <hip/hip_runtime.h>
#include <hip/hip_bf16.h>
#include <math.h>

#define NH 8
#define HS 64
#define VOCAB 16384
#define QPH 2048                         // queries per head = b(4) * t(512)
#define NSLICE 32                        // vocab slices (512 rows each)
// fold 1/sqrt(512) * log2(e) into Q so the epilogue is p = exp2(score)
#define QSCALE (0.04419417382415922f * 1.4426950408889634f)

typedef __attribute__((ext_vector_type(8))) short bf16x8;
typedef __attribute__((ext_vector_type(4))) float f32x4;

static __device__ __forceinline__ unsigned short f2bf(float f) {
    __hip_bfloat16 h = __float2bfloat16(f);
    unsigned short u;
    __builtin_memcpy(&u, &h, 2);
    return u;
}

static __device__ __forceinline__ float fexp2(float x) {
#if __has_builtin(__builtin_amdgcn_exp2f)
    return __builtin_amdgcn_exp2f(x);     // v_exp_f32 directly
#else
    return __expf(x * 0.6931471805599453f);
#endif
}

// async global->LDS: dest is wave-uniform base + lane*16 (m104); src is per-lane.
static __device__ __forceinline__ void stage16(const void* g, void* l) {
    __builtin_amdgcn_global_load_lds(
        (const __attribute__((address_space(1))) void*)g,
        (__attribute__((address_space(3))) void*)l, 16, 0, 0);
}

// ---------------- Kernel 1a: eprep — E -> bf16 (FRAG-ORDERED) + g[n][v] -------------
// R11: ebf layout is MFMA-fragment order so attn can global_load_lds it LINEARLY and
// ds_read_b128 at (lane*16 + const) with zero conflicts and zero swizzle math:
//   shorts addr = ((((n*1024 + T)*2 + h)*4 + q)*16 + r)*8 + j
//   where v = T*16 + r, c(head-dim col) = h*32 + q*8 + j.
// One 16-row v-tile = 2048 B: [khalf h][quad q][row r][8 shorts] — chunk(q*16+r)=16 B
// is exactly what lane (q,r) feeds to mfma_16x16x32 as A.
__global__ void eprep(const float* __restrict__ emb, const float* __restrict__ dec_w,
                      unsigned short* __restrict__ ebf, float* __restrict__ g) {
    int i4  = blockIdx.x * 256 + threadIdx.x;   // float4 index, total 2097152
    int row = i4 >> 4;                          // n*16384 + v
    int c4  = i4 & 15;                          // float4 within row, c = c4*4
    int n   = row >> 14;
    int v   = row & (VOCAB - 1);
    f32x4 vv = ((const f32x4*)emb)[i4];
    ushort4 u = make_ushort4(f2bf(vv.x), f2bf(vv.y), f2bf(vv.z), f2bf(vv.w));
    int T = v >> 4, r = v & 15;
    int h = c4 >> 3, q = (c4 >> 1) & 3, jh = c4 & 1;
    size_t o4 = ((((size_t)(n * 1024 + T) * 2 + h) * 4 + q) * 16 + r) * 2 + jh;
    ((ushort4*)ebf)[o4] = u;
    const float* dw = dec_w + n * 64 + c4 * 4;
    float p = vv.x * dw[0] + vv.y * dw[1] + vv.z * dw[2] + vv.w * dw[3];
    p += __shfl_xor(p, 1); p += __shfl_xor(p, 2);
    p += __shfl_xor(p, 4); p += __shfl_xor(p, 8);
    if (c4 == 0) g[row] = p;
}

// ---------------- Kernel 1b: qprep — Q = LayerNorm(enc(x)+PE) * QSCALE -> bf16 -------
__global__ void qprep(const float* __restrict__ x, const float* __restrict__ enc_w,
                      const float* __restrict__ enc_b, const float* __restrict__ ln_w,
                      const float* __restrict__ ln_b, unsigned short* __restrict__ qbf) {
    int row  = blockIdx.x * 4 + (threadIdx.x >> 6);  // n*2048 + q
    int h    = threadIdx.x & 63;
    int n = row >> 11;
    int q = row & 2047;
    int t = q & 511;
    float xv = x[q];
    int d = n * 64 + h;
    float h2  = (float)(h & ~1);
    float div = __expf(h2 * (-9.210340371976184f / 64.0f));
    float ang = (float)t * div;
    float pe  = (h & 1) ? __cosf(ang) : __sinf(ang);
    float v = xv * enc_w[d] + enc_b[d] + pe;
    float s = v;
    #pragma unroll
    for (int off = 1; off < 64; off <<= 1) s += __shfl_xor(s, off);
    float mu = s * (1.0f / 64.0f);
    float dd = v - mu;
    float s2 = dd * dd;
    #pragma unroll
    for (int off = 1; off < 64; off <<= 1) s2 += __shfl_xor(s2, off);
    float var = s2 * (1.0f / 64.0f);
    float y = dd * rsqrtf(var + 1e-5f) * ln_w[h] + ln_b[h];
    qbf[row * 64 + h] = f2bf(y * QSCALE);
}

// ---------------- Kernel 2: attn (R11 — LDS double-buffer + one-tranche) -------------
// grid 1024 = qchunk(4)*256 + vslice(32)*8 + head(8); block 256 (4 waves).
// blockIdx % 8 == head: each XCD's share touches ONE head's E (2MB < 4MB L2).
// R11 changes vs R9 (61us, MfmaUtil 22%, Occupancy 24%):
//  - E comes via frag-ordered global_load_lds (1 instr/thread/iter, 4KB/block/iter),
//    double-buffered one iteration ahead; __syncthreads() is the vmcnt(0) drain.
//    Removes the per-iter L2 load-use stall AND the 4x per-wave redundant E reads.
//  - ds_read_b128 at smem + (it&1)*4096 + lane*16 + {0,1024,2048,3072}: linear,
//    conflict-free, 1 address VGPR (was 4+ global pointers).
//  - g staged once to LDS (2KB) — no global loads left in the K-loop.
//  - __launch_bounds__(256,4): 4 blocks/CU -> grid 1024 fully co-resident, NO tail
//    (R9's (256,3) ran 768-block tranche @37.5% + 256-block tail @12.5% = 24% avg).
//    Reg cap 128: Q(64)+afrag(16)+num/den(16)+gv(8)+addr(~10) fits. TRIPWIRE: if
//    WRITE_SIZE >> 4MB the cap spilled Q (R4); if VGPR<=90 Q is being re-loaded.
//  - K-loop still NOT unrolled (R5 guard).
__global__ void __launch_bounds__(256, 4)
attn(const unsigned short* __restrict__ qbf, const unsigned short* __restrict__ ebf,
     const float* __restrict__ g, float2* __restrict__ part) {
    __shared__ __attribute__((aligned(16))) char smem[2 * 4096 + 2048];
    float* gl = (float*)(smem + 8192);

    int tid  = threadIdx.x;
    int w    = tid >> 6;
    int lane = tid & 63;
    int quad = lane >> 4;
    int l15  = lane & 15;
    int head   = blockIdx.x & 7;
    int vslice = (blockIdx.x >> 3) & 31;   // 32 slices x 512 rows
    int qchunk = blockIdx.x >> 8;          // 4 chunks x 512 q
    int qbase  = (qchunk * 4 + w) * 128;   // 128 q per wave

    // frag-ordered E source for this (head, vslice): 32 tiles x 2048 B
    const char* esrc = (const char*)ebf + (size_t)(head * 1024 + vslice * 32) * 2048;
    const float* gp  = g + head * VOCAB + vslice * 512;

    // prologue: stage iter0 E tile (4KB) + g slice (2KB)
    stage16(esrc + tid * 16, smem + w * 1024);
    ((float2*)gl)[tid] = ((const float2*)gp)[tid];

    // persistent Q B-frags: B[k=hs][n=q], lane: n=l15, k = kf*32 + quad*8 + j
    const short* qp = (const short*)qbf + (size_t)(head * QPH + qbase) * HS;
    bf16x8 qf[8][2];
    #pragma unroll
    for (int qt = 0; qt < 8; ++qt) {
        const short* qrow = qp + (qt * 16 + l15) * HS + quad * 8;
        qf[qt][0] = *(const bf16x8*)(qrow);
        qf[qt][1] = *(const bf16x8*)(qrow + 32);
    }

    float num[8] = {0.f, 0.f, 0.f, 0.f, 0.f, 0.f, 0.f, 0.f};
    float den[8] = {0.f, 0.f, 0.f, 0.f, 0.f, 0.f, 0.f, 0.f};
    const f32x4 z = {0.f, 0.f, 0.f, 0.f};

    __syncthreads();   // drains stage16(iter0) + g ds_writes (vmcnt/lgkmcnt 0)

    #pragma clang loop unroll(disable)
    for (int it = 0; it < 16; ++it) {
        // prefetch next E tile into the other buffer (issued before compute)
        if (it < 15)
            stage16(esrc + (it + 1) * 4096 + tid * 16,
                    smem + ((it + 1) & 1) * 4096 + w * 1024);

        const char* abase = smem + (it & 1) * 4096 + lane * 16;
        bf16x8 a00 = *(const bf16x8*)(abase);           // tile0, k 0..31
        bf16x8 a01 = *(const bf16x8*)(abase + 1024);    // tile0, k 32..63
        bf16x8 a10 = *(const bf16x8*)(abase + 2048);    // tile1, k 0..31
        bf16x8 a11 = *(const bf16x8*)(abase + 3072);    // tile1, k 32..63
        f32x4 gv0 = *(const f32x4*)(gl + it * 32 + quad * 4);
        f32x4 gv1 = *(const f32x4*)(gl + it * 32 + 16 + quad * 4);

        #pragma unroll
        for (int qt = 0; qt < 8; ++qt) {
            f32x4 acc0 = __builtin_amdgcn_mfma_f32_16x16x32_bf16(a00, qf[qt][0], z, 0, 0, 0);
            acc0       = __builtin_amdgcn_mfma_f32_16x16x32_bf16(a01, qf[qt][1], acc0, 0, 0, 0);
            f32x4 acc1 = __builtin_amdgcn_mfma_f32_16x16x32_bf16(a10, qf[qt][0], z, 0, 0, 0);
            acc1       = __builtin_amdgcn_mfma_f32_16x16x32_bf16(a11, qf[qt][1], acc1, 0, 0, 0);
            // D layout: col=l15=q, row=quad*4+r = v-within-16-tile
            #pragma unroll
            for (int r = 0; r < 4; ++r) {
                float p0 = fexp2(acc0[r]);
                float p1 = fexp2(acc1[r]);
                den[qt] += p0 + p1;
                num[qt] += p0 * gv0[r] + p1 * gv1[r];
            }
        }
        // __syncthreads emits s_waitcnt vmcnt(0) lgkmcnt(0) + s_barrier:
        // prefetch has landed, all waves done reading buf — safe to swap.
        __syncthreads();
    }

    // reduce across quads (same l15 = same q)
    #pragma unroll
    for (int qt = 0; qt < 8; ++qt) {
        num[qt] += __shfl_xor(num[qt], 16); num[qt] += __shfl_xor(num[qt], 32);
        den[qt] += __shfl_xor(den[qt], 16); den[qt] += __shfl_xor(den[qt], 32);
    }
    // slotted partials (no atomics): part[vslice][head][q]; quad commits 2 tiles
    #pragma unroll
    for (int j = 0; j < 2; ++j) {
        int qt = quad * 2 + j;
        int qg = qbase + qt * 16 + l15;
        part[((size_t)vslice * NH + head) * QPH + qg] = make_float2(num[qt], den[qt]);
    }
}

// ---------------- Kernel 3: fin — parallel over (n,q), LDS reduce over n -------------
__global__ void fin(const float2* __restrict__ part, const float* __restrict__ dec_b,
                    float* __restrict__ out) {
    __shared__ float red[8][32];
    int t  = threadIdx.x;
    int ql = t & 31;
    int n  = t >> 5;
    int q  = blockIdx.x * 32 + ql;
    float nv = 0.f, dv = 0.f;
    #pragma unroll 8
    for (int sl = 0; sl < NSLICE; ++sl) {
        float2 nd = part[((size_t)sl * NH + n) * QPH + q];
        nv += nd.x; dv += nd.y;
    }
    red[n][ql] = nv / dv;
    __syncthreads();
    if (t < 32) {
        float s = dec_b[0];
        #pragma unroll
        for (int m = 0; m < NH; ++m) s += red[m][t];
        out[q] = s;
    }
}

extern "C" void kernel_launch(void* const* d_in, const int* in_sizes, int n_in,
                              void* d_out, int out_size, void* d_ws, size_t ws_size,
                              hipStream_t stream) {
    const float* x     = (const float*)d_in[0];
    const float* emb   = (const float*)d_in[1];
    const float* enc_w = (const float*)d_in[2];
    const float* enc_b = (const float*)d_in[3];
    const float* ln_w  = (const float*)d_in[4];
    const float* ln_b  = (const float*)d_in[5];
    const float* dec_w = (const float*)d_in[6];
    const float* dec_b = (const float*)d_in[7];
    float* out = (float*)d_out;

    char* ws = (char*)d_ws;
    unsigned short* qbf  = (unsigned short*)(ws);                        // 2 MB
    unsigned short* ebf  = (unsigned short*)(ws + 2097152);              // 16 MB
    float*          g    = (float*)(ws + 2097152 + 16777216);            // 512 KB
    float2*         part = (float2*)(ws + 2097152 + 16777216 + 524288);  // 4 MB

    hipLaunchKernelGGL(eprep, dim3(8192), dim3(256), 0, stream, emb, dec_w, ebf, g);
    hipLaunchKernelGGL(qprep, dim3(4096), dim3(256), 0, stream, x, enc_w, enc_b, ln_w, ln_b, qbf);
    hipLaunchKernelGGL(attn,  dim3(1024), dim3(256), 0, stream, qbf, ebf, g, part);
    hipLaunchKernelGGL(fin,   dim3(64),   dim3(256), 0, stream, part, dec_b, out);
}

// Round 3
// 141.115 us; speedup vs baseline: 1.1001x; 1.1001x over previous
//
#include <hip/hip_runtime.h>
#include <hip/hip_bf16.h>
#include <math.h>

#define NH 8
#define HS 64
#define VOCAB 16384
#define QPH 2048                         // queries per head = b(4) * t(512)
#define NSLICE 32                        // vocab slices (512 rows each)
// fold 1/sqrt(512) * log2(e) into Q so the epilogue is p = exp2(score)
#define QSCALE (0.04419417382415922f * 1.4426950408889634f)

typedef __attribute__((ext_vector_type(8))) short bf16x8;
typedef __attribute__((ext_vector_type(4))) float f32x4;

static __device__ __forceinline__ unsigned short f2bf(float f) {
    __hip_bfloat16 h = __float2bfloat16(f);
    unsigned short u;
    __builtin_memcpy(&u, &h, 2);
    return u;
}

static __device__ __forceinline__ float fexp2(float x) {
#if __has_builtin(__builtin_amdgcn_exp2f)
    return __builtin_amdgcn_exp2f(x);     // v_exp_f32 directly
#else
    return __expf(x * 0.6931471805599453f);
#endif
}

// async global->LDS. HW semantics (m104): LDS dest = WAVE-UNIFORM base + lane*16.
// R13 FIX vs R12: dest must be passed wave-uniform (R12 passed tid-divergent
// pointers — SGPR operand, risks a waterfall loop / fault). Src stays per-lane.
static __device__ __forceinline__ void stage16(const void* g, void* l) {
    __builtin_amdgcn_global_load_lds(
        (const __attribute__((address_space(1))) void*)g,
        (__attribute__((address_space(3))) void*)l, 16, 0, 0);
}

// ---------------- Kernel 1a: eprep — E -> bf16 (FRAG-ORDERED, GATHER) + g -----------
// Gather form — thread OWNS output chunk (linear coalesced ushort4 write), reads the
// permuted input f32x4 (32B segments, L2-absorbed). Layout:
//   ushort4 chunk o4 = (n*1024+T)*256 + h*128 + q*32 + r*2 + jh
//   holds E[v=T*16+r][c = h*32 + q*8 + jh*4 .. +3] as 4 bf16.
// One 2048B tile T = [kf h][quad q][row r][jh] — byte kf*1024+q*256+r*16+jh*8, i.e.
// exactly lane(q,r)'s 16B A-frag at (lane*16 + kf*1024).
// g[n][v] = E[n][v,:].dec_w via per-block LDS reduction (block == one (n,T) tile).
__global__ void eprep(const float* __restrict__ emb, const float* __restrict__ dec_w,
                      unsigned short* __restrict__ ebf, float* __restrict__ g) {
    __shared__ float red[256];
    int tid = threadIdx.x;
    int nt  = blockIdx.x;                 // n*1024 + T  (grid 8192)
    int h   = (tid >> 7) & 1;
    int q   = (tid >> 5) & 3;
    int r   = (tid >> 1) & 15;
    int jh  = tid & 1;
    int n   = nt >> 10;
    int T   = nt & 1023;
    int row = n * VOCAB + T * 16 + r;
    int c4  = h * 8 + q * 2 + jh;         // f32x4 column index
    f32x4 vv = ((const f32x4*)emb)[(size_t)row * 16 + c4];
    ushort4 u = make_ushort4(f2bf(vv.x), f2bf(vv.y), f2bf(vv.z), f2bf(vv.w));
    ((ushort4*)ebf)[(size_t)nt * 256 + tid] = u;   // linear, coalesced
    const float* dw = dec_w + n * 64 + c4 * 4;
    float p = vv.x * dw[0] + vv.y * dw[1] + vv.z * dw[2] + vv.w * dw[3];
    red[tid] = p;
    __syncthreads();
    if (tid < 16) {                       // thread tid sums row r=tid over 16 c4 slots
        float s = 0.f;
        #pragma unroll
        for (int m = 0; m < 16; ++m)
            s += red[((m >> 3) * 128) + (((m & 7) >> 1) * 32) + tid * 2 + (m & 1)];
        g[n * VOCAB + T * 16 + tid] = s;
    }
}

// ---------------- Kernel 1b: qprep — LayerNorm(enc(x)+PE)*QSCALE -> bf16 (FRAG-ORD) -
// Output frag-ordered per 128-q group so attn can global_load_lds Q linearly and
// ds_read_b128 at (lane*16 + immediate):
//   short idx = (head*16 + q>>7)*8192 + ((qt*2+kf)*4 + quad)*128 + l15*8 + j
//   where qt=(q>>4)&7, l15=q&15, kf=h>>5, quad=(h>>3)&3, j=h&7.
__global__ void qprep(const float* __restrict__ x, const float* __restrict__ enc_w,
                      const float* __restrict__ enc_b, const float* __restrict__ ln_w,
                      const float* __restrict__ ln_b, unsigned short* __restrict__ qbf) {
    int row  = blockIdx.x * 4 + (threadIdx.x >> 6);  // n*2048 + q
    int h    = threadIdx.x & 63;
    int n = row >> 11;
    int q = row & 2047;
    int t = q & 511;
    float xv = x[q];
    int d = n * 64 + h;
    float h2  = (float)(h & ~1);
    float div = __expf(h2 * (-9.210340371976184f / 64.0f));
    float ang = (float)t * div;
    float pe  = (h & 1) ? __cosf(ang) : __sinf(ang);
    float v = xv * enc_w[d] + enc_b[d] + pe;
    float s = v;
    #pragma unroll
    for (int off = 1; off < 64; off <<= 1) s += __shfl_xor(s, off);
    float mu = s * (1.0f / 64.0f);
    float dd = v - mu;
    float s2 = dd * dd;
    #pragma unroll
    for (int off = 1; off < 64; off <<= 1) s2 += __shfl_xor(s2, off);
    float var = s2 * (1.0f / 64.0f);
    float y = dd * rsqrtf(var + 1e-5f) * ln_w[h] + ln_b[h];
    int qt   = (q >> 4) & 7;
    int l15  = q & 15;
    int kf   = h >> 5;
    int quad = (h >> 3) & 3;
    int j    = h & 7;
    size_t idx = ((size_t)(n * 16 + (q >> 7)) * 8192)
               + ((size_t)((qt * 2 + kf) * 4 + quad) * 128) + l15 * 8 + j;
    qbf[idx] = f2bf(y * QSCALE);
}

// ---------------- Kernel 2: attn (R13 — Q in shared LDS, barrier-free K-loop) --------
// grid 1024 = vgroup(8)*128 + qgroup(16)*8 + head(8); block 256 (4 waves).
// blockIdx % 8 == head: XCD-pinned — head's ebf (2MB) + qbf (256KB) + g (64KB) L2-fit.
// Block covers 128 q x 2048 v: Q (16KB, frag-ordered) SHARED in LDS by all 4 waves;
// wave w owns v-slice vgroup*4+w (512 v, 8 iters x 64 v).
// vs R9/R11 (61-63us, Occ 24-28%, Q-spill battles):
//  - NO persistent Q in VGPRs (R4/R10/R11: compiler spills 64-reg arrays across
//    barrier loops). Q frags re-read from LDS per use — transient, unspillable.
//    asm memory clobber per iter blocks LICM from re-hoisting them (would re-spill).
//  - NO barrier in the K-loop (Q/g read-only after one prologue barrier). The per-iter
//    __syncthreads vmcnt(0) convoy is gone; waves drift freely.
//  - E A-frags direct global->VGPR from L2: frag-ordered ebf makes each load ONE
//    coalesced 1KB dwordx4 at base+lane*16. 64 v/iter; Q-LDS reads amortize 1:4.
//  - LDS 24KB, launch_bounds(256,4): grid 1024 fully co-resident, ONE tranche.
//    TRIPWIRE: WRITE_SIZE >> 4MB => spill came back; VGPR should be ~96-128.
__global__ void __launch_bounds__(256, 4)
attn(const unsigned short* __restrict__ qbf, const unsigned short* __restrict__ ebf,
     const float* __restrict__ g, float2* __restrict__ part) {
    __shared__ __attribute__((aligned(16))) char smem[16384 + 8192];
    float* gl = (float*)(smem + 16384);

    int tid  = threadIdx.x;
    int w    = tid >> 6;
    int lane = tid & 63;
    int quad = lane >> 4;
    int l15  = lane & 15;
    int head   = blockIdx.x & 7;
    int qgroup = (blockIdx.x >> 3) & 15;   // 16 groups x 128 q
    int vgroup = blockIdx.x >> 7;          // 8 groups x 2048 v
    int vslice = vgroup * 4 + w;           // global 512-v slice id (0..31)

    const char*  qsrc = (const char*)qbf + (size_t)(head * 16 + qgroup) * 16384;
    const char*  esrc = (const char*)ebf + (size_t)head * 2097152 + (size_t)vslice * 65536;
    const float* gp   = g + head * VOCAB + vgroup * 2048;

    // prologue: stage Q (16KB) + g (8KB); dest is WAVE-UNIFORM (+w*1024), HW adds
    // lane*16 -> lane l of wave w lands at byte tid*16 exactly. ONE barrier total.
    #pragma unroll
    for (int k = 0; k < 4; ++k)
        stage16(qsrc + k * 4096 + tid * 16, smem + k * 4096 + w * 1024);
    stage16((const char*)gp + tid * 16,        (char*)gl + w * 1024);
    stage16((const char*)gp + 4096 + tid * 16, (char*)gl + 4096 + w * 1024);
    __syncthreads();   // s_waitcnt vmcnt(0) lgkmcnt(0) + s_barrier

    float num[8] = {0.f, 0.f, 0.f, 0.f, 0.f, 0.f, 0.f, 0.f};
    float den[8] = {0.f, 0.f, 0.f, 0.f, 0.f, 0.f, 0.f, 0.f};
    const f32x4 z = {0.f, 0.f, 0.f, 0.f};
    const float* gw = gl + w * 512;

    #pragma clang loop unroll(disable)
    for (int it = 0; it < 8; ++it) {
        // block LICM: without this the compiler hoists the loop-invariant Q ds_reads
        // (64 VGPRs) out of the loop and spills them to scratch (R11 failure mode).
        asm volatile("" ::: "memory");
        const char* eb = esrc + it * 8192;
        bf16x8 a[4][2];
        #pragma unroll
        for (int vt = 0; vt < 4; ++vt) {
            a[vt][0] = *(const bf16x8*)(eb + vt * 2048 +        lane * 16);
            a[vt][1] = *(const bf16x8*)(eb + vt * 2048 + 1024 + lane * 16);
        }
        f32x4 gv[4];
        #pragma unroll
        for (int vt = 0; vt < 4; ++vt)
            gv[vt] = *(const f32x4*)(gw + it * 64 + vt * 16 + quad * 4);

        #pragma unroll
        for (int qt = 0; qt < 8; ++qt) {
            const char* qb = smem + qt * 2048 + lane * 16;
            bf16x8 q0 = *(const bf16x8*)(qb);
            bf16x8 q1 = *(const bf16x8*)(qb + 1024);
            #pragma unroll
            for (int vt = 0; vt < 4; ++vt) {
                f32x4 acc = __builtin_amdgcn_mfma_f32_16x16x32_bf16(a[vt][0], q0, z, 0, 0, 0);
                acc       = __builtin_amdgcn_mfma_f32_16x16x32_bf16(a[vt][1], q1, acc, 0, 0, 0);
                // D layout: col=l15=q, row=quad*4+r = v-within-16-tile
                #pragma unroll
                for (int r = 0; r < 4; ++r) {
                    float p = fexp2(acc[r]);
                    den[qt] += p;
                    num[qt] += p * gv[vt][r];
                }
            }
        }
    }

    // reduce across quads (same l15 = same q)
    #pragma unroll
    for (int qt = 0; qt < 8; ++qt) {
        num[qt] += __shfl_xor(num[qt], 16); num[qt] += __shfl_xor(num[qt], 32);
        den[qt] += __shfl_xor(den[qt], 16); den[qt] += __shfl_xor(den[qt], 32);
    }
    // slotted partials (no atomics): part[vslice][head][q]; quad commits 2 q-tiles
    #pragma unroll
    for (int j = 0; j < 2; ++j) {
        int qt = quad * 2 + j;
        int qg = qgroup * 128 + qt * 16 + l15;
        part[((size_t)vslice * NH + head) * QPH + qg] = make_float2(num[qt], den[qt]);
    }
}

// ---------------- Kernel 3: fin — parallel over (n,q), LDS reduce over n -------------
__global__ void fin(const float2* __restrict__ part, const float* __restrict__ dec_b,
                    float* __restrict__ out) {
    __shared__ float red[8][32];
    int t  = threadIdx.x;
    int ql = t & 31;
    int n  = t >> 5;
    int q  = blockIdx.x * 32 + ql;
    float nv = 0.f, dv = 0.f;
    #pragma unroll 8
    for (int sl = 0; sl < NSLICE; ++sl) {
        float2 nd = part[((size_t)sl * NH + n) * QPH + q];
        nv += nd.x; dv += nd.y;
    }
    red[n][ql] = nv / dv;
    __syncthreads();
    if (t < 32) {
        float s = dec_b[0];
        #pragma unroll
        for (int m = 0; m < NH; ++m) s += red[m][t];
        out[q] = s;
    }
}

extern "C" void kernel_launch(void* const* d_in, const int* in_sizes, int n_in,
                              void* d_out, int out_size, void* d_ws, size_t ws_size,
                              hipStream_t stream) {
    const float* x     = (const float*)d_in[0];
    const float* emb   = (const float*)d_in[1];
    const float* enc_w = (const float*)d_in[2];
    const float* enc_b = (const float*)d_in[3];
    const float* ln_w  = (const float*)d_in[4];
    const float* ln_b  = (const float*)d_in[5];
    const float* dec_w = (const float*)d_in[6];
    const float* dec_b = (const float*)d_in[7];
    float* out = (float*)d_out;

    char* ws = (char*)d_ws;
    unsigned short* qbf  = (unsigned short*)(ws);                        // 2 MB
    unsigned short* ebf  = (unsigned short*)(ws + 2097152);              // 16 MB
    float*          g    = (float*)(ws + 2097152 + 16777216);            // 512 KB
    float2*         part = (float2*)(ws + 2097152 + 16777216 + 524288);  // 4 MB

    hipLaunchKernelGGL(eprep, dim3(8192), dim3(256), 0, stream, emb, dec_w, ebf, g);
    hipLaunchKernelGGL(qprep, dim3(4096), dim3(256), 0, stream, x, enc_w, enc_b, ln_w, ln_b, qbf);
    hipLaunchKernelGGL(attn,  dim3(1024), dim3(256), 0, stream, qbf, ebf, g, part);
    hipLaunchKernelGGL(fin,   dim3(64),   dim3(256), 0, stream, part, dec_b, out);
}